// Round 2
// baseline (10339.595 us; speedup 1.0000x reference)
//
#include <hip/hip_runtime.h>
#include <stdint.h>

// FlashRNN fused LSTM, MI355X persistent kernel, round 2.
//
// Round-1 post-mortem: 10.1 us/step dominated by a 256-WG all-to-all flag
// barrier (memory-side round trips + max-of-256 skew) and a per-step agent
// acquire fence (buffer_inv -> L1+L2 invalidate; FETCH_SIZE 5x ideal).
//
// Round-2 design:
//  - Batches are independent: WG w (grp=w&7, sub=w>>3) serves batches
//    {2grp, 2grp+1} x 24 d-columns. Sync group = 32 WGs with same grp
//    (XCD-aligned under round-robin dispatch; correctness placement-free).
//  - R register-stationary: lane (g=lane>>4, kg=lane&15, wave wv) holds
//    R[g][48kg..48kg+48)[cb+6wv..+6) = 288 floats. No replication.
//  - h consumed via agent-scope relaxed ATOMIC loads (bypass L1/L2, read
//    the memory-side point the publishes wrote) -> NO buffer_inv fence.
//  - One __syncthreads per step. Wave 0 alone does pointwise update +
//    publish: h stores -> s_waitcnt vmcnt(0) -> flag -> c stores.
//  - flags monotonic (poison 0xAA = negative int -> poll f>=t+1 safe).

typedef float f32x2 __attribute__((ext_vector_type(2)));

#define NWG   256
#define NTHR  256
#define T_    1024
#define TP1   1025
#define B_    16
#define D_    768
#define NG_   4
#define SUBS  32          // WGs per sync group
#define CPW   24          // d-columns per WG
#define EPL   6           // cols per lane
#define KPL   48          // k per lane
#define BPW   2           // batches per WG

__device__ __forceinline__ float sigm(float x) { return 1.0f / (1.0f + __expf(-x)); }
__device__ __forceinline__ float tanh_f(float x) {
  float e = __expf(2.0f * x);
  return 1.0f - 2.0f / (e + 1.0f);
}

template <int CTRL>
__device__ __forceinline__ float dpp_ror_add(float x) {
  int xi = __builtin_bit_cast(int, x);
  int yi = __builtin_amdgcn_update_dpp(0, xi, CTRL, 0xF, 0xF, false);
  return x + __builtin_bit_cast(float, yi);
}
// sum across the 16 lanes of a DPP row; all lanes end with the total
__device__ __forceinline__ float row_reduce16(float x) {
  x = dpp_ror_add<0x128>(x);   // row_ror:8
  x = dpp_ror_add<0x124>(x);   // row_ror:4
  x = dpp_ror_add<0x122>(x);   // row_ror:2
  x = dpp_ror_add<0x121>(x);   // row_ror:1
  return x;
}

__global__ __launch_bounds__(NTHR, 1) void flashrnn_fused(
    const float* __restrict__ states,   // [2][16][768]
    const float* __restrict__ Wx,       // [16][1024][4][768]
    const float* __restrict__ Rw,       // [4][768][768]
    const float* __restrict__ bias,     // [4][768]
    float* __restrict__ out,            // [2][16][1025][768]
    int* __restrict__ flags)            // [256] in d_ws
{
  const int wg   = blockIdx.x;
  const int tid  = threadIdx.x;
  const int grp  = wg & 7;
  const int sub  = wg >> 3;
  const int wv   = tid >> 6;
  const int lane = tid & 63;
  const int g    = lane >> 4;
  const int kg   = lane & 15;
  const int cb   = sub * CPW;          // WG's absolute col base
  const int b0   = grp * BPW;          // WG's first batch

  __shared__ float glds[2][BPW][NG_][CPW];

  // update-lane identity (wave 0, lanes 0..47)
  const int ub   = lane / CPW;         // batch-in-WG
  const int ue   = lane % CPW;         // col-in-WG
  const int ucol = cb + ue;
  const int ubb  = b0 + ub;
  float c_reg = 0.0f;
  float b4[NG_] = {0.f, 0.f, 0.f, 0.f};

  // ---- init: wave 0 publishes h0/c0 for owned (b,col), then flag=1 ----
  if (wv == 0) {
    if (lane < BPW * CPW) {
      #pragma unroll
      for (int gg = 0; gg < NG_; ++gg) b4[gg] = bias[gg * D_ + ucol];
      float h0 = states[(size_t)ubb * D_ + ucol];
      c_reg    = states[(size_t)(B_ + ubb) * D_ + ucol];
      __hip_atomic_store(&out[((size_t)ubb * TP1) * D_ + ucol], h0,
                         __ATOMIC_RELAXED, __HIP_MEMORY_SCOPE_AGENT);
      out[((size_t)(B_ + ubb) * TP1) * D_ + ucol] = c_reg;
    }
    asm volatile("s_waitcnt vmcnt(0)" ::: "memory");
    if (tid == 0)
      __hip_atomic_store(&flags[wg], 1, __ATOMIC_RELAXED,
                         __HIP_MEMORY_SCOPE_AGENT);
  }

  // ---- stationary R: r2[p][e] = R[g][48kg+2p(+1)][cb + 6wv + e] ----
  f32x2 r2[24][EPL];
  const int ce = cb + wv * EPL;
  #pragma unroll
  for (int p = 0; p < 24; ++p) {
    const int k0 = KPL * kg + 2 * p;
    #pragma unroll
    for (int e = 0; e < EPL; ++e) {
      f32x2 v;
      v.x = Rw[((size_t)g * D_ + k0    ) * D_ + ce + e];
      v.y = Rw[((size_t)g * D_ + k0 + 1) * D_ + ce + e];
      r2[p][e] = v;
    }
  }

  // ---- main recurrence ------------------------------------------------
  for (int t = 0; t < T_; ++t) {
    // poll own group's 32 flags >= t+1 (h_t published)
    const int target = t + 1;
    for (;;) {
      int f = target;
      if (lane < SUBS)
        f = __hip_atomic_load(&flags[(lane << 3) | grp], __ATOMIC_RELAXED,
                              __HIP_MEMORY_SCOPE_AGENT);
      if (__ballot(f >= target) == ~0ull) break;
      __builtin_amdgcn_s_sleep(1);
    }
    __atomic_signal_fence(__ATOMIC_ACQUIRE);  // compiler-only: no hoisting

    // wave 0 update lanes: issue this step's Wx loads early (plain, cached)
    float wx[NG_] = {0.f, 0.f, 0.f, 0.f};
    if (wv == 0 && lane < BPW * CPW) {
      #pragma unroll
      for (int gg = 0; gg < NG_; ++gg)
        wx[gg] = Wx[(((size_t)ubb * T_ + t) * NG_ + gg) * D_ + ucol];
    }

    // matvec: acc[b][e] += h[b][k-pair] * R[g][k-pair][ce+e]
    f32x2 acc[BPW][EPL];
    #pragma unroll
    for (int b = 0; b < BPW; ++b)
      #pragma unroll
      for (int e = 0; e < EPL; ++e) { acc[b][e].x = 0.f; acc[b][e].y = 0.f; }

    #pragma unroll
    for (int b = 0; b < BPW; ++b) {
      const float* hrow = out + ((size_t)(b0 + b) * TP1 + t) * D_ + KPL * kg;
      unsigned long long hv[24];
      #pragma unroll
      for (int p = 0; p < 24; ++p)
        hv[p] = __hip_atomic_load(
            (const unsigned long long*)(hrow + 2 * p), __ATOMIC_RELAXED,
            __HIP_MEMORY_SCOPE_AGENT);
      #pragma unroll
      for (int p = 0; p < 24; ++p) {
        f32x2 h2 = __builtin_bit_cast(f32x2, hv[p]);
        #pragma unroll
        for (int e = 0; e < EPL; ++e)
          acc[b][e] = __builtin_elementwise_fma(h2, r2[p][e], acc[b][e]);
      }
    }

    // cross-kg reduce; kg==0 lanes deposit gates to LDS (double-buffered)
    const int buf = t & 1;
    #pragma unroll
    for (int b = 0; b < BPW; ++b)
      #pragma unroll
      for (int e = 0; e < EPL; ++e) {
        float v = acc[b][e].x + acc[b][e].y;
        v = row_reduce16(v);
        if (kg == 0) glds[buf][b][g][wv * EPL + e] = v;
      }
    __syncthreads();

    // wave 0: pointwise update + publish h_{t+1}; others roll to next poll
    if (wv == 0) {
      float hn = 0.f;
      if (lane < BPW * CPW) {
        const float pi = wx[0] + glds[buf][ub][0][ue] + b4[0];
        const float pf = wx[1] + glds[buf][ub][1][ue] + b4[1];
        const float pz = wx[2] + glds[buf][ub][2][ue] + b4[2];
        const float po = wx[3] + glds[buf][ub][3][ue] + b4[3];
        const float ig = sigm(pi), fg = sigm(pf);
        const float zg = tanh_f(pz), og = sigm(po);
        c_reg = fg * c_reg + ig * zg;
        hn = og * tanh_f(c_reg);
        __hip_atomic_store(&out[((size_t)ubb * TP1 + t + 1) * D_ + ucol], hn,
                           __ATOMIC_RELAXED, __HIP_MEMORY_SCOPE_AGENT);
      }
      asm volatile("s_waitcnt vmcnt(0)" ::: "memory");  // drain h publishes
      if (tid == 0)
        __hip_atomic_store(&flags[wg], t + 2, __ATOMIC_RELAXED,
                           __HIP_MEMORY_SCOPE_AGENT);
      if (lane < BPW * CPW)  // c not consumed cross-WG: store after flag
        out[((size_t)(B_ + ubb) * TP1 + t + 1) * D_ + ucol] = c_reg;
    }
  }
}

extern "C" void kernel_launch(void* const* d_in, const int* in_sizes, int n_in,
                              void* d_out, int out_size, void* d_ws, size_t ws_size,
                              hipStream_t stream) {
  const float* states = (const float*)d_in[0];
  const float* Wx     = (const float*)d_in[1];
  const float* Rw     = (const float*)d_in[2];
  const float* bias   = (const float*)d_in[3];
  float* out          = (float*)d_out;
  int* flags          = (int*)d_ws;   // 1 KB; 0xAA poison = negative ints

  flashrnn_fused<<<dim3(NWG), dim3(NTHR), 0, stream>>>(states, Wx, Rw, bias,
                                                       out, flags);
}

// Round 3
// 6340.459 us; speedup vs baseline: 1.6307x; 1.6307x over previous
//
#include <hip/hip_runtime.h>
#include <stdint.h>

// FlashRNN fused LSTM, MI355X persistent kernel, round 3.
//
// Round-2 finding: step time (10.1 us) is dominated by flag-poll latency at
// FIXED addresses; __hip_atomic_load(AGENT) polls appear to be served by a
// stale cache line until eviction (~9 us), insensitive to sync-group size.
// h loads at fresh addresses each step were always correct -> data path OK,
// observation path broken.
//
// Round-3 design:
//  - Exchange h via TAGGED 8B packets ((t+1)<<32 | f32bits) in d_ws,
//    double-buffered by t&1. Tag self-validates arrival: no separate flag,
//    no producer-side vmcnt drain, ONE visibility hop per step.
//  - All exchange loads/stores are inline-asm global_*_dwordx2 sc0 sc1
//    (guaranteed L1+L2 bypass -> LLC round trip, no stale-line spin).
//  - Overwrite safety of 2-slot buffer: producer writes slot (t+1)&1 only
//    after consuming ALL tags t+1 => every WG published h_t => every WG
//    fully consumed h_{t-1}. Poison 0xAA never matches tags 1..1025.
//  - Per WG (grp=wg&7, sub=wg>>3): batches {2grp,2grp+1}, cols [24sub,+24).
//    R register-stationary (288 f32/lane). Each thread polls 6 packets,
//    fills LDS (padded [2][16][50] -> conflict-free ds_read_b64 by kg),
//    all 4 waves matvec, DPP row-reduce, wave 0 updates + publishes.
//  - out[] history is written with PLAIN cached stores (nobody reads it
//    in-kernel anymore).

typedef float f32x2 __attribute__((ext_vector_type(2)));

#define NWG   256
#define NTHR  256
#define T_    1024
#define TP1   1025
#define B_    16
#define D_    768
#define NG_   4
#define CPW   24          // d-columns per WG
#define EPL   6           // cols per lane (per wave)
#define KPL   48          // k per lane
#define BPW   2           // batches per WG

__device__ __forceinline__ float sigm(float x) { return 1.0f / (1.0f + __expf(-x)); }
__device__ __forceinline__ float tanh_f(float x) {
  float e = __expf(2.0f * x);
  return 1.0f - 2.0f / (e + 1.0f);
}

template <int CTRL>
__device__ __forceinline__ float dpp_ror_add(float x) {
  int xi = __builtin_bit_cast(int, x);
  int yi = __builtin_amdgcn_update_dpp(0, xi, CTRL, 0xF, 0xF, false);
  return x + __builtin_bit_cast(float, yi);
}
// sum across the 16 lanes of a DPP row; all lanes end with the total
__device__ __forceinline__ float row_reduce16(float x) {
  x = dpp_ror_add<0x128>(x);
  x = dpp_ror_add<0x124>(x);
  x = dpp_ror_add<0x122>(x);
  x = dpp_ror_add<0x121>(x);
  return x;
}

// ---- LLC-coherent exchange primitives (bypass L1+L2) --------------------
__device__ __forceinline__ void ld_u64_cc(unsigned long long& r,
                                          const unsigned long long* p) {
  asm volatile("global_load_dwordx2 %0, %1, off sc0 sc1" : "=v"(r) : "v"(p));
}
__device__ __forceinline__ void st_u64_cc(unsigned long long* p,
                                          unsigned long long v) {
  asm volatile("global_store_dwordx2 %0, %1, off sc0 sc1" ::"v"(p), "v"(v)
               : "memory");
}
__device__ __forceinline__ void wait_vm0() {
  asm volatile("s_waitcnt vmcnt(0)" ::: "memory");
  __builtin_amdgcn_sched_barrier(0);   // rule 18: no hoisting past the wait
}

__global__ __launch_bounds__(NTHR, 1) void flashrnn_fused(
    const float* __restrict__ states,   // [2][16][768]
    const float* __restrict__ Wx,       // [16][1024][4][768]
    const float* __restrict__ Rw,       // [4][768][768]
    const float* __restrict__ bias,     // [4][768]
    float* __restrict__ out,            // [2][16][1025][768]
    unsigned long long* __restrict__ hx)  // [2][16][768] tagged packets (d_ws)
{
  const int wg   = blockIdx.x;
  const int tid  = threadIdx.x;
  const int grp  = wg & 7;
  const int sub  = wg >> 3;
  const int wv   = tid >> 6;
  const int lane = tid & 63;
  const int g    = lane >> 4;
  const int kg   = lane & 15;
  const int cb   = sub * CPW;
  const int b0   = grp * BPW;

  // padded LDS: h rows stride 50 -> kg-strided ds_read_b64 is conflict-free
  __shared__ float h_lds[BPW][16][50];
  __shared__ float glds[2][BPW][NG_][CPW];

  // update-lane identity (wave 0, lanes 0..47)
  const int ub   = lane / CPW;
  const int ue   = lane % CPW;
  const int ucol = cb + ue;
  const int ubb  = b0 + ub;
  float c_reg = 0.0f;
  float b4[NG_] = {0.f, 0.f, 0.f, 0.f};

  // ---- init: wave 0 publishes tagged h0 (tag=1), plain h0/c0 to out ----
  if (wv == 0 && lane < BPW * CPW) {
    #pragma unroll
    for (int gg = 0; gg < NG_; ++gg) b4[gg] = bias[gg * D_ + ucol];
    float h0 = states[(size_t)ubb * D_ + ucol];
    c_reg    = states[(size_t)(B_ + ubb) * D_ + ucol];
    unsigned long long pkt =
        (1ull << 32) | (unsigned long long)__float_as_uint(h0);
    st_u64_cc(&hx[(size_t)ubb * D_ + ucol], pkt);   // slot 0
    out[((size_t)ubb * TP1) * D_ + ucol] = h0;
    out[((size_t)(B_ + ubb) * TP1) * D_ + ucol] = c_reg;
  }

  // ---- stationary R: r2[p][e] = R[g][48kg+2p(+1)][cb + 6wv + e] ----
  f32x2 r2[24][EPL];
  const int ce = cb + wv * EPL;
  #pragma unroll
  for (int p = 0; p < 24; ++p) {
    const int k0 = KPL * kg + 2 * p;
    #pragma unroll
    for (int e = 0; e < EPL; ++e) {
      f32x2 v;
      v.x = Rw[((size_t)g * D_ + k0    ) * D_ + ce + e];
      v.y = Rw[((size_t)g * D_ + k0 + 1) * D_ + ce + e];
      r2[p][e] = v;
    }
  }

  // ---- per-thread poll identity: packets j = 6*tid .. 6*tid+5 ----------
  // b = tid>=128, k0 = 6*(tid&127); LDS target row K=(tid&127)>>3, r=6*(tid&7)
  const int pb  = tid >> 7;           // batch-in-WG being polled
  const int pk0 = 6 * (tid & 127);    // first k polled
  const int pK  = (tid & 127) >> 3;
  const int pr  = 6 * (tid & 7);

  // ---- main recurrence ------------------------------------------------
  for (int t = 0; t < T_; ++t) {
    // (A) wave 0: issue this step's Wx loads early (plain cached)
    float wx[NG_] = {0.f, 0.f, 0.f, 0.f};
    if (wv == 0 && lane < BPW * CPW) {
      #pragma unroll
      for (int gg = 0; gg < NG_; ++gg)
        wx[gg] = Wx[(((size_t)ubb * T_ + t) * NG_ + gg) * D_ + ucol];
    }

    // (B) poll own 6 tagged packets of h_t (tag == t+1) from LLC
    const unsigned long long* pbase =
        hx + ((size_t)(t & 1) * B_ + (b0 + pb)) * D_ + pk0;
    unsigned long long v[6];
    const unsigned want = (unsigned)(t + 1);
    #pragma unroll
    for (int j = 0; j < 6; ++j) ld_u64_cc(v[j], pbase + j);
    wait_vm0();
    unsigned mask = 0;
    for (;;) {
      #pragma unroll
      for (int j = 0; j < 6; ++j)
        if (!(mask & (1u << j)) && (unsigned)(v[j] >> 32) == want)
          mask |= 1u << j;
      if (mask == 0x3Fu) break;
      #pragma unroll
      for (int j = 0; j < 6; ++j)
        if (!(mask & (1u << j))) ld_u64_cc(v[j], pbase + j);
      wait_vm0();
    }

    // (C) deposit h_t into LDS
    #pragma unroll
    for (int j = 0; j < 6; ++j)
      h_lds[pb][pK][pr + j] = __uint_as_float((unsigned)v[j]);

    // (D) barrier 1: h_t staged
    __syncthreads();

    // (E) matvec: acc[b][e] = sum over lane's 48 k of h[b][k]*R[g][k][ce+e]
    f32x2 acc[BPW][EPL];
    #pragma unroll
    for (int b = 0; b < BPW; ++b)
      #pragma unroll
      for (int e = 0; e < EPL; ++e) { acc[b][e].x = 0.f; acc[b][e].y = 0.f; }

    #pragma unroll
    for (int b = 0; b < BPW; ++b) {
      const float* hp = &h_lds[b][kg][0];
      #pragma unroll
      for (int p = 0; p < 24; ++p) {
        f32x2 h2 = *(const f32x2*)(hp + 2 * p);
        #pragma unroll
        for (int e = 0; e < EPL; ++e)
          acc[b][e] = __builtin_elementwise_fma(h2, r2[p][e], acc[b][e]);
      }
    }

    // cross-kg reduce; kg==0 deposits gates (double-buffered glds)
    const int buf = t & 1;
    #pragma unroll
    for (int b = 0; b < BPW; ++b)
      #pragma unroll
      for (int e = 0; e < EPL; ++e) {
        float s = acc[b][e].x + acc[b][e].y;
        s = row_reduce16(s);
        if (kg == 0) glds[buf][b][g][wv * EPL + e] = s;
      }

    // (F) barrier 2: gates staged
    __syncthreads();

    // (G) wave 0: pointwise update + tagged publish + plain history stores
    if (wv == 0 && lane < BPW * CPW) {
      const float pi = wx[0] + glds[buf][ub][0][ue] + b4[0];
      const float pf = wx[1] + glds[buf][ub][1][ue] + b4[1];
      const float pz = wx[2] + glds[buf][ub][2][ue] + b4[2];
      const float po = wx[3] + glds[buf][ub][3][ue] + b4[3];
      const float ig = sigm(pi), fg = sigm(pf);
      const float zg = tanh_f(pz), og = sigm(po);
      c_reg = fg * c_reg + ig * zg;
      const float hn = og * tanh_f(c_reg);
      unsigned long long pkt = (((unsigned long long)(unsigned)(t + 2)) << 32) |
                               (unsigned long long)__float_as_uint(hn);
      st_u64_cc(&hx[((size_t)((t + 1) & 1) * B_ + ubb) * D_ + ucol], pkt);
      out[((size_t)ubb * TP1 + t + 1) * D_ + ucol] = hn;            // plain
      out[((size_t)(B_ + ubb) * TP1 + t + 1) * D_ + ucol] = c_reg;  // plain
    }
  }
}

extern "C" void kernel_launch(void* const* d_in, const int* in_sizes, int n_in,
                              void* d_out, int out_size, void* d_ws, size_t ws_size,
                              hipStream_t stream) {
  const float* states = (const float*)d_in[0];
  const float* Wx     = (const float*)d_in[1];
  const float* Rw     = (const float*)d_in[2];
  const float* bias   = (const float*)d_in[3];
  float* out          = (float*)d_out;
  unsigned long long* hx = (unsigned long long*)d_ws;  // 192 KB tagged stage

  flashrnn_fused<<<dim3(NWG), dim3(NTHR), 0, stream>>>(states, Wx, Rw, bias,
                                                       out, hx);
}

// Round 4
// 5253.407 us; speedup vs baseline: 1.9682x; 1.2069x over previous
//
#include <hip/hip_runtime.h>
#include <stdint.h>

// FlashRNN fused LSTM, MI355X persistent kernel, round 4.
//
// Round-3 finding: tagged-packet exchange works (6.34 ms) but every thread
// polls 6 x 8B data packets with vmcnt(0) per retry -> 12 KB/WG/retry of
// LLC traffic, serialized LLC round trips, and 2x payload (tag per value).
//
// Round-4 design: split control from data.
//  - Control: per-producer 4B flags (flags[grp][sub]), sc0 sc1 both sides.
//    Poll = 1 dword/lane (128B/wave/retry). Monotonic; 0xAA poison negative.
//  - Data: h history lives in out[] only. Producer stores h with sc0 sc1
//    (write-through to LLC), vmcnt(0), THEN posts flag. Consumers read h
//    with PLAIN CACHED loads: safe because each h_t address is written
//    exactly once and only ever read after the flag confirms the LLC
//    write (fresh line -> L2 fill pulls new data; nothing stale to hit).
//    32 consumer WGs of a group share the XCD L2 fill -> 32x less LLC
//    data traffic vs round 3.
//  - No LDS h staging, no tag unpacking, one barrier per step.
//  - Partition unchanged (proven): WG (grp=wg&7, sub=wg>>3) serves batches
//    {2grp,2grp+1} x cols [24sub, 24sub+24). R register-stationary
//    (288 f32/lane, AGPR+VGPR unified file). DPP row_ror reduce over kg.

typedef float f32x2 __attribute__((ext_vector_type(2)));

#define NWG   256
#define NTHR  256
#define T_    1024
#define TP1   1025
#define B_    16
#define D_    768
#define NG_   4
#define CPW   24          // d-columns per WG
#define EPL   6           // cols per lane (per wave)
#define KPL   48          // k per lane
#define BPW   2           // batches per WG

__device__ __forceinline__ float sigm(float x) { return 1.0f / (1.0f + __expf(-x)); }
__device__ __forceinline__ float tanh_f(float x) {
  float e = __expf(2.0f * x);
  return 1.0f - 2.0f / (e + 1.0f);
}

template <int CTRL>
__device__ __forceinline__ float dpp_ror_add(float x) {
  int xi = __builtin_bit_cast(int, x);
  int yi = __builtin_amdgcn_update_dpp(0, xi, CTRL, 0xF, 0xF, false);
  return x + __builtin_bit_cast(float, yi);
}
// sum across the 16 lanes of a DPP row; all lanes end with the total
__device__ __forceinline__ float row_reduce16(float x) {
  x = dpp_ror_add<0x128>(x);
  x = dpp_ror_add<0x124>(x);
  x = dpp_ror_add<0x122>(x);
  x = dpp_ror_add<0x121>(x);
  return x;
}

// ---- LLC-coherent primitives (bypass L1+L2) ----------------------------
__device__ __forceinline__ int ld_flag_cc(const int* p) {
  int r;
  asm volatile("global_load_dword %0, %1, off sc0 sc1" : "=v"(r) : "v"(p));
  return r;
}
__device__ __forceinline__ void st_u32_cc(float* p, float v) {
  asm volatile("global_store_dword %0, %1, off sc0 sc1" ::"v"(p), "v"(v)
               : "memory");
}
__device__ __forceinline__ void st_i32_cc(int* p, int v) {
  asm volatile("global_store_dword %0, %1, off sc0 sc1" ::"v"(p), "v"(v)
               : "memory");
}
__device__ __forceinline__ void wait_vm0() {
  asm volatile("s_waitcnt vmcnt(0)" ::: "memory");
  __builtin_amdgcn_sched_barrier(0);   // rule 18: pin scheduling at the wait
}

__global__ __launch_bounds__(NTHR, 1) void flashrnn_fused(
    const float* __restrict__ states,   // [2][16][768]
    const float* __restrict__ Wx,       // [16][1024][4][768]
    const float* __restrict__ Rw,       // [4][768][768]
    const float* __restrict__ bias,     // [4][768]
    float* __restrict__ out,            // [2][16][1025][768]
    int* __restrict__ flags)            // [8][32] in d_ws
{
  const int wg   = blockIdx.x;
  const int tid  = threadIdx.x;
  const int grp  = wg & 7;
  const int sub  = wg >> 3;
  const int wv   = tid >> 6;
  const int lane = tid & 63;
  const int g    = lane >> 4;
  const int kg   = lane & 15;
  const int cb   = sub * CPW;
  const int b0   = grp * BPW;

  __shared__ float glds[2][BPW][NG_][CPW];   // gate partials, double-buffered

  // update-lane identity (wave 0, lanes 0..47)
  const int ub   = lane / CPW;
  const int ue   = lane % CPW;
  const int ucol = cb + ue;
  const int ubb  = b0 + ub;
  float c_reg = 0.0f;
  float b4[NG_] = {0.f, 0.f, 0.f, 0.f};

  // ---- init: wave 0 publishes h0 (write-through), then flag=1 ----------
  if (wv == 0) {
    if (lane < BPW * CPW) {
      #pragma unroll
      for (int gg = 0; gg < NG_; ++gg) b4[gg] = bias[gg * D_ + ucol];
      float h0 = states[(size_t)ubb * D_ + ucol];
      c_reg    = states[(size_t)(B_ + ubb) * D_ + ucol];
      st_u32_cc(&out[((size_t)ubb * TP1) * D_ + ucol], h0);
      out[((size_t)(B_ + ubb) * TP1) * D_ + ucol] = c_reg;
    }
    wait_vm0();
    if (tid == 0) st_i32_cc(&flags[grp * 32 + sub], 1);
  }

  // ---- stationary R: r2[p][e] = R[g][48kg+2p(+1)][cb + 6wv + e] --------
  f32x2 r2[24][EPL];
  const int ce = cb + wv * EPL;
  #pragma unroll
  for (int p = 0; p < 24; ++p) {
    const int k0 = KPL * kg + 2 * p;
    #pragma unroll
    for (int e = 0; e < EPL; ++e) {
      f32x2 v;
      v.x = Rw[((size_t)g * D_ + k0    ) * D_ + ce + e];
      v.y = Rw[((size_t)g * D_ + k0 + 1) * D_ + ce + e];
      r2[p][e] = v;
    }
  }

  const int* myflag = flags + grp * 32 + (lane & 31);

  // ---- main recurrence -------------------------------------------------
  for (int t = 0; t < T_; ++t) {
    // (A) wave 0: issue this step's Wx loads early (plain cached)
    float wx[NG_] = {0.f, 0.f, 0.f, 0.f};
    if (wv == 0 && lane < BPW * CPW) {
      #pragma unroll
      for (int gg = 0; gg < NG_; ++gg)
        wx[gg] = Wx[(((size_t)ubb * T_ + t) * NG_ + gg) * D_ + ucol];
    }

    // (B) poll group's 32 flags >= t+1 (one dword per lane, sc0 sc1)
    const int target = t + 1;
    for (;;) {
      int f = ld_flag_cc(myflag);
      wait_vm0();
      if (__ballot(f >= target) == ~0ull) break;
      __builtin_amdgcn_s_sleep(1);
    }
    __builtin_amdgcn_sched_barrier(0);   // no hoisting of h loads above poll

    // (C) matvec from PLAIN cached h loads (fresh addresses; L2-amortized)
    f32x2 acc[BPW][EPL];
    #pragma unroll
    for (int b = 0; b < BPW; ++b)
      #pragma unroll
      for (int e = 0; e < EPL; ++e) { acc[b][e].x = 0.f; acc[b][e].y = 0.f; }

    #pragma unroll
    for (int b = 0; b < BPW; ++b) {
      const float* hrow = out + ((size_t)(b0 + b) * TP1 + t) * D_ + KPL * kg;
      f32x2 h2[24];
      #pragma unroll
      for (int p = 0; p < 24; ++p) h2[p] = *(const f32x2*)(hrow + 2 * p);
      #pragma unroll
      for (int p = 0; p < 24; ++p) {
        #pragma unroll
        for (int e = 0; e < EPL; ++e)
          acc[b][e] = __builtin_elementwise_fma(h2[p], r2[p][e], acc[b][e]);
      }
    }

    // cross-kg reduce; kg==0 deposits gate partials (double-buffered glds)
    const int buf = t & 1;
    #pragma unroll
    for (int b = 0; b < BPW; ++b)
      #pragma unroll
      for (int e = 0; e < EPL; ++e) {
        float s = acc[b][e].x + acc[b][e].y;
        s = row_reduce16(s);
        if (kg == 0) glds[buf][b][g][wv * EPL + e] = s;
      }

    // (D) barrier: gates staged
    __syncthreads();

    // (E) wave 0: pointwise update, publish h_{t+1} (cc) -> drain -> flag
    if (wv == 0) {
      float hn = 0.f;
      if (lane < BPW * CPW) {
        const float pi = wx[0] + glds[buf][ub][0][ue] + b4[0];
        const float pf = wx[1] + glds[buf][ub][1][ue] + b4[1];
        const float pz = wx[2] + glds[buf][ub][2][ue] + b4[2];
        const float po = wx[3] + glds[buf][ub][3][ue] + b4[3];
        const float ig = sigm(pi), fg = sigm(pf);
        const float zg = tanh_f(pz), og = sigm(po);
        c_reg = fg * c_reg + ig * zg;
        hn = og * tanh_f(c_reg);
        st_u32_cc(&out[((size_t)ubb * TP1 + t + 1) * D_ + ucol], hn);
      }
      wait_vm0();                        // h_{t+1} at LLC before flag
      if (tid == 0) st_i32_cc(&flags[grp * 32 + sub], t + 2);
      if (lane < BPW * CPW)              // c not consumed cross-WG
        out[((size_t)(B_ + ubb) * TP1 + t + 1) * D_ + ucol] = c_reg;
    }
  }
}

extern "C" void kernel_launch(void* const* d_in, const int* in_sizes, int n_in,
                              void* d_out, int out_size, void* d_ws, size_t ws_size,
                              hipStream_t stream) {
  const float* states = (const float*)d_in[0];
  const float* Wx     = (const float*)d_in[1];
  const float* Rw     = (const float*)d_in[2];
  const float* bias   = (const float*)d_in[3];
  float* out          = (float*)d_out;
  int* flags          = (int*)d_ws;   // 1 KB; 0xAA poison = negative ints

  flashrnn_fused<<<dim3(NWG), dim3(NTHR), 0, stream>>>(states, Wx, Rw, bias,
                                                       out, flags);
}